// Round 16
// baseline (145.605 us; speedup 1.0000x reference)
//
#include <hip/hip_runtime.h>
#include <hip/hip_bf16.h>
#include <stdint.h>

#define H 16
#define D 128
#define BM 256      // q rows per block (8 warps x 32)
#define BN 64       // kv rows per tile
#define NT 512

typedef __bf16 bf16_t;
typedef bf16_t bf16x8 __attribute__((ext_vector_type(8)));
typedef float f32x16 __attribute__((ext_vector_type(16)));

#define MFMA32(a, b, c) __builtin_amdgcn_mfma_f32_32x32x16_bf16(a, b, c, 0, 0, 0)

union FragU { uint32_t w[4]; bf16x8 v; };

static __device__ __forceinline__ uint32_t cvtpk_bf16(float lo, float hi) {
  uint32_t r;
  asm("v_cvt_pk_bf16_f32 %0, %1, %2" : "=v"(r) : "v"(lo), "v"(hi));
  return r;
}

static __device__ __forceinline__ void gld_lds16(const bf16_t* g, bf16_t* l) {
  __builtin_amdgcn_global_load_lds(
      (const __attribute__((address_space(1))) void*)g,
      (__attribute__((address_space(3))) void*)l, 16, 0, 0);
}

// cross-half exchange: lane i receives v[i^32] (verified round 15)
static __device__ __forceinline__ float xhalf(float v, int hi) {
  uint32_t b = __builtin_bit_cast(uint32_t, v);
  auto p = __builtin_amdgcn_permlane32_swap(b, b, false, false);
  uint32_t o = hi ? p[0] : p[1];
  return __builtin_bit_cast(float, o);
}

// ---------------- convert kernels (one-time per launch) ----------------

__global__ void conv_k(const float* __restrict__ kin, bf16_t* __restrict__ kb, int n8) {
  int i = blockIdx.x * blockDim.x + threadIdx.x;
  int stride = gridDim.x * blockDim.x;
  for (; i < n8; i += stride) {
    const float* p = kin + (size_t)i * 8;
    float4 a = *(const float4*)p, b = *(const float4*)(p + 4);
    bf16x8 w;
    w[0] = (bf16_t)a.x; w[1] = (bf16_t)a.y; w[2] = (bf16_t)a.z; w[3] = (bf16_t)a.w;
    w[4] = (bf16_t)b.x; w[5] = (bf16_t)b.y; w[6] = (bf16_t)b.z; w[7] = (bf16_t)b.w;
    *(bf16x8*)(kb + (size_t)i * 8) = w;
  }
}

__global__ void conv_vt(const float* __restrict__ v, bf16_t* __restrict__ vt,
                        const int* __restrict__ cuk, int nseq) {
  int tile = blockIdx.x, h = blockIdx.y;
  int acc = 0, seq = -1, lt = 0, s0k = 0, Lk = 0, Lkp = 0;
  size_t vb = 0;
  for (int s = 0; s < nseq; ++s) {
    int Ls = cuk[s + 1] - cuk[s];
    int Lp = (Ls + 63) & ~63;
    int nt = Lp / 64;
    if (tile < acc + nt) { seq = s; lt = tile - acc; s0k = cuk[s]; Lk = Ls; Lkp = Lp; break; }
    acc += nt; vb += (size_t)H * D * Lp;
  }
  if (seq < 0) return;
  int kv0 = lt * 64;
  int d = threadIdx.x;
  bf16x8 w[8];
  #pragma unroll
  for (int j = 0; j < 64; ++j) {
    int kv = kv0 + j;
    int kvc = kv < Lk ? kv : Lk - 1;
    float val = v[((size_t)(s0k + kvc) * H + h) * D + d];
    w[j >> 3][j & 7] = (bf16_t)val;
  }
  bf16_t* dstT = vt + vb + (size_t)h * D * Lkp + (size_t)lt * 8192;
  #pragma unroll
  for (int c = 0; c < 8; ++c)
    *(bf16x8*)(dstT + ((size_t)c * 128 + d) * 8) = w[c];
}

// ---------------- main kernel: split-KV units (round-15 core) ----------------

__global__ __launch_bounds__(NT, 2)
void fa_split(const float* __restrict__ q,
              const bf16_t* __restrict__ kb,
              const bf16_t* __restrict__ vt,
              const int* __restrict__ cuq,
              const int* __restrict__ cuk,
              float* __restrict__ out,
              bf16_t* __restrict__ pO,
              float* __restrict__ pm,
              float* __restrict__ pl,
              int nseq, int maxt, int upb)
{
  __shared__ alignas(16) bf16_t sK[2][BN * D];
  __shared__ alignas(16) bf16_t sVt[3][8 * 128 * 8];

  const int nwg = gridDim.x;
  const int orig = blockIdx.x;
  const int qq = nwg >> 3, rr = nwg & 7;
  const int xcd = orig & 7;
  const int wgid = (xcd < rr ? xcd * (qq + 1) : rr * (qq + 1) + (xcd - rr) * qq) + (orig >> 3);
  const int u = wgid % upb;
  const int h = wgid / upb;

  int accU = 0, accT = 0, seq = -1, qtile = 0, chunk = 0, tileIdx = 0;
  int s0q = 0, s0k = 0, Lq = 0, Lk = 0, Lkp = 0, nkv = 0, cs = 1;
  size_t vb = 0;
  for (int s = 0; s < nseq; ++s) {
    int a = cuq[s], b = cuq[s + 1];
    int Ls = b - a;
    int nt = (Ls + BM - 1) / BM;
    int Lks = cuk[s + 1] - cuk[s];
    int Lp = (Lks + 63) & ~63;
    int nk = (Lks + 63) / 64;
    int c2 = nk > 8 ? 2 : 1;
    if (u < accU + nt * c2) {
      int local = u - accU;
      seq = s; chunk = local / nt; qtile = local % nt; tileIdx = accT + qtile;
      s0q = a; Lq = Ls; s0k = cuk[s]; Lk = Lks; Lkp = Lp; nkv = nk; cs = c2;
      break;
    }
    accU += nt * c2; accT += nt; vb += (size_t)H * D * Lp;
  }
  if (seq < 0) return;

  const int t0 = chunk * 8;
  const int t1 = (chunk == 0) ? (nkv < 8 ? nkv : 8) : nkv;

  const int q0 = qtile * BM;
  const int tid = threadIdx.x;
  const int lane = tid & 63;
  const int lq = lane & 31;
  const int hi = lane >> 5;
  const int warp = tid >> 6;

  const float SC = 0.08838834764831845f * 1.44269504088896340f;

  bf16x8 qf[8];
  {
    int qrow = q0 + warp * 32 + lq; if (qrow >= Lq) qrow = Lq - 1;
    const float* qp = q + ((size_t)(s0q + qrow) * H + h) * D;
    #pragma unroll
    for (int ks = 0; ks < 8; ++ks) {
      const float* p = qp + ks * 16 + hi * 8;
      float4 a = *(const float4*)p, b = *(const float4*)(p + 4);
      bf16x8 r;
      r[0] = (bf16_t)(a.x * SC); r[1] = (bf16_t)(a.y * SC);
      r[2] = (bf16_t)(a.z * SC); r[3] = (bf16_t)(a.w * SC);
      r[4] = (bf16_t)(b.x * SC); r[5] = (bf16_t)(b.y * SC);
      r[6] = (bf16_t)(b.z * SC); r[7] = (bf16_t)(b.w * SC);
      qf[ks] = r;
    }
  }

  const bf16_t* vsrcH = vt + vb + (size_t)h * D * Lkp;

  auto STAGE_K = [&](int tt, int buf) {
    const int kvb = tt * BN;
    #pragma unroll
    for (int i = 0; i < 2; ++i) {
      int g = tid + i * NT;
      int row = g >> 4, cc = g & 15;
      int kvr = kvb + row; if (kvr >= Lk) kvr = Lk - 1;
      const bf16_t* src = kb + ((size_t)(s0k + kvr) * H + h) * D + ((cc ^ (row & 7)) << 3);
      gld_lds16(src, &sK[buf][g * 8]);
    }
  };
  auto STAGE_V = [&](int tt, int buf) {
    const bf16_t* vsrc = vsrcH + (size_t)tt * 8192;
    #pragma unroll
    for (int i = 0; i < 2; ++i) {
      int g = tid + i * NT;
      gld_lds16(vsrc + (size_t)g * 8, &sVt[buf][g * 8]);
    }
  };

  f32x16 oacc[4];
  #pragma unroll
  for (int dt = 0; dt < 4; ++dt)
    #pragma unroll
    for (int r = 0; r < 16; ++r) oacc[dt][r] = 0.f;
  float m = -1e30f, l = 0.f;

  FragU paP, pbP;
  #pragma unroll
  for (int i = 0; i < 4; ++i) { paP.w[i] = 0u; pbP.w[i] = 0u; }
  float alphaP = 1.0f;
  int tP = t0, ctP = 0;

  STAGE_K(t0, t0 & 1);
  STAGE_V(t0, t0 % 3);
  asm volatile("s_waitcnt vmcnt(0)" ::: "memory");
  __builtin_amdgcn_s_barrier();
  __builtin_amdgcn_sched_barrier(0);

  for (int t = t0; t < t1; ++t) {
    const int kvb = t * BN;
    int tn = t + 1 < t1 ? t + 1 : t1 - 1;
    STAGE_K(tn, (t + 1) & 1);
    STAGE_V(tn, (t + 1) % 3);

    const bf16_t* sKc = sK[t & 1];
    const bool tail = (kvb + BN > Lk);

    #pragma unroll
    for (int ct = 0; ct < 2; ++ct) {
      f32x16 sa, sb;
      #pragma unroll
      for (int r = 0; r < 16; ++r) { sa[r] = 0.f; sb[r] = 0.f; }
      int krow = ct * 32 + lq;
      __builtin_amdgcn_s_setprio(1);
      #pragma unroll
      for (int ks = 0; ks < 4; ++ks) {
        int posa = (ks * 2 + hi) ^ (krow & 7);
        bf16x8 kfa = *(const bf16x8*)&sKc[krow * 128 + (posa << 3)];
        sa = MFMA32(kfa, qf[ks], sa);
        int posb = ((ks + 4) * 2 + hi) ^ (krow & 7);
        bf16x8 kfb = *(const bf16x8*)&sKc[krow * 128 + (posb << 3)];
        sb = MFMA32(kfb, qf[ks + 4], sb);
      }
      __builtin_amdgcn_s_setprio(0);

      // PV(p-1)
      if (__any(alphaP != 1.0f)) {
        #pragma unroll
        for (int r = 0; r < 16; ++r) {
          int cr = (r & 3) + 8 * (r >> 2) + 4 * hi;
          float a2 = __shfl(alphaP, cr);
          #pragma unroll
          for (int dt = 0; dt < 4; ++dt) oacc[dt][r] *= a2;
        }
      }
      {
        const bf16_t* sVp = sVt[tP % 3];
        #pragma unroll
        for (int dt = 0; dt < 4; ++dt) {
          int drow = dt * 32 + lq;
          bf16x8 vf0 = *(const bf16x8*)&sVp[((ctP * 4 + hi) * 128 + drow) << 3];
          oacc[dt] = MFMA32(paP.v, vf0, oacc[dt]);
          bf16x8 vf1 = *(const bf16x8*)&sVp[((ctP * 4 + 2 + hi) * 128 + drow) << 3];
          oacc[dt] = MFMA32(pbP.v, vf1, oacc[dt]);
        }
      }

      // softmax(p)
      f32x16 st;
      #pragma unroll
      for (int r = 0; r < 16; ++r) {
        float x = sa[r] + sb[r];
        if (tail) {
          int kvi = kvb + ct * 32 + (r & 3) + 8 * (r >> 2) + 4 * hi;
          if (kvi >= Lk) x = -1e30f;
        }
        st[r] = x;
      }
      float m0;
      {
        float a0 = fmaxf(st[0], st[1]),  a1 = fmaxf(st[2], st[3]);
        float a2 = fmaxf(st[4], st[5]),  a3 = fmaxf(st[6], st[7]);
        float a4 = fmaxf(st[8], st[9]),  a5 = fmaxf(st[10], st[11]);
        float a6 = fmaxf(st[12], st[13]), a7 = fmaxf(st[14], st[15]);
        float b0 = fmaxf(a0, a1), b1 = fmaxf(a2, a3);
        float b2 = fmaxf(a4, a5), b3 = fmaxf(a6, a7);
        m0 = fmaxf(fmaxf(b0, b1), fmaxf(b2, b3));
      }
      float m1 = fmaxf(m0, xhalf(m0, hi));
      bool trig = m1 > m + 8.0f;
      float mnew = trig ? m1 : m;
      float alpha = __builtin_amdgcn_exp2f(m - mnew);
      m = mnew;

      #pragma unroll
      for (int r = 0; r < 16; ++r)
        st[r] = __builtin_amdgcn_exp2f(st[r] - m);
      float psum;
      {
        float a0 = st[0] + st[1],  a1 = st[2] + st[3];
        float a2 = st[4] + st[5],  a3 = st[6] + st[7];
        float a4 = st[8] + st[9],  a5 = st[10] + st[11];
        float a6 = st[12] + st[13], a7 = st[14] + st[15];
        float b0 = a0 + a1, b1 = a2 + a3, b2 = a4 + a5, b3 = a6 + a7;
        psum = (b0 + b1) + (b2 + b3);
      }
      psum += xhalf(psum, hi);
      l = l * alpha + psum;

      uint32_t c0 = cvtpk_bf16(st[0],  st[1]),  c1 = cvtpk_bf16(st[2],  st[3]);
      uint32_t c2 = cvtpk_bf16(st[4],  st[5]),  c3 = cvtpk_bf16(st[6],  st[7]);
      uint32_t c4 = cvtpk_bf16(st[8],  st[9]),  c5 = cvtpk_bf16(st[10], st[11]);
      uint32_t c6 = cvtpk_bf16(st[12], st[13]), c7 = cvtpk_bf16(st[14], st[15]);
      { auto w2 = __builtin_amdgcn_permlane32_swap(c0, c2, false, false); c0 = w2[0]; c2 = w2[1]; }
      { auto w2 = __builtin_amdgcn_permlane32_swap(c1, c3, false, false); c1 = w2[0]; c3 = w2[1]; }
      { auto w2 = __builtin_amdgcn_permlane32_swap(c4, c6, false, false); c4 = w2[0]; c6 = w2[1]; }
      { auto w2 = __builtin_amdgcn_permlane32_swap(c5, c7, false, false); c5 = w2[0]; c7 = w2[1]; }
      paP.w[0] = c0; paP.w[1] = c1; paP.w[2] = c2; paP.w[3] = c3;
      pbP.w[0] = c4; pbP.w[1] = c5; pbP.w[2] = c6; pbP.w[3] = c7;
      alphaP = alpha; tP = t; ctP = ct;
    }

    asm volatile("s_waitcnt vmcnt(2)" ::: "memory");
    __builtin_amdgcn_s_barrier();
    __builtin_amdgcn_sched_barrier(0);
  }

  // final pipelined PV
  if (__any(alphaP != 1.0f)) {
    #pragma unroll
    for (int r = 0; r < 16; ++r) {
      int cr = (r & 3) + 8 * (r >> 2) + 4 * hi;
      float a2 = __shfl(alphaP, cr);
      #pragma unroll
      for (int dt = 0; dt < 4; ++dt) oacc[dt][r] *= a2;
    }
  }
  {
    const bf16_t* sVp = sVt[tP % 3];
    #pragma unroll
    for (int dt = 0; dt < 4; ++dt) {
      int drow = dt * 32 + lq;
      bf16x8 vf0 = *(const bf16x8*)&sVp[((ctP * 4 + hi) * 128 + drow) << 3];
      oacc[dt] = MFMA32(paP.v, vf0, oacc[dt]);
      bf16x8 vf1 = *(const bf16x8*)&sVp[((ctP * 4 + 2 + hi) * 128 + drow) << 3];
      oacc[dt] = MFMA32(pbP.v, vf1, oacc[dt]);
    }
  }

  if (cs == 2) {
    // ---- partial epilogue: unnormalized O (bf16) + per-row m,l ----
    const size_t slot = (size_t)(h * maxt + tileIdx) * 2 + chunk;
    bf16_t* po = pO + slot * (256 * 128);
    #pragma unroll
    for (int r = 0; r < 16; ++r) {
      int cr = (r & 3) + 8 * (r >> 2) + 4 * hi;
      int row = warp * 32 + cr;
      #pragma unroll
      for (int dt = 0; dt < 4; ++dt)
        po[row * 128 + dt * 32 + lq] = (bf16_t)oacc[dt][r];
    }
    if (hi == 0) {
      pm[slot * 256 + warp * 32 + lq] = m;
      pl[slot * 256 + warp * 32 + lq] = l;
    }
  } else {
    // ---- direct epilogue ----
    #pragma unroll
    for (int r = 0; r < 16; ++r) {
      int cr = (r & 3) + 8 * (r >> 2) + 4 * hi;
      int qr = q0 + warp * 32 + cr;
      float lcr = __shfl(l, cr);
      if (qr < Lq) {
        float rn = 1.0f / lcr;
        float* op = out + ((size_t)(s0q + qr) * H + h) * D + lq;
        #pragma unroll
        for (int dt = 0; dt < 4; ++dt)
          op[dt * 32] = oacc[dt][r] * rn;
      }
    }
  }
}

// ---------------- combine kernel ----------------

__global__ __launch_bounds__(256)
void fa_combine(const int* __restrict__ cuq, const int* __restrict__ cuk,
                const bf16_t* __restrict__ pO, const float* __restrict__ pm,
                const float* __restrict__ pl, float* __restrict__ out,
                int nseq, int maxt)
{
  int gt = blockIdx.x >> 2;        // tile-slot 0..maxt*H-1
  int rg = blockIdx.x & 3;
  int h = gt / maxt;
  int tileIdx = gt % maxt;

  int accT = 0, seq = -1, qtile = 0, s0q = 0, Lq = 0, nkv = 0;
  for (int s = 0; s < nseq; ++s) {
    int a = cuq[s], b = cuq[s + 1];
    int Ls = b - a;
    int nt = (Ls + BM - 1) / BM;
    if (tileIdx < accT + nt) {
      seq = s; qtile = tileIdx - accT; s0q = a; Lq = Ls;
      nkv = (cuk[s + 1] - cuk[s] + 63) / 64;
      break;
    }
    accT += nt;
  }
  if (seq < 0 || nkv <= 8) return;   // unsplit tiles already wrote out

  int tid = threadIdx.x;
  int row = rg * 64 + (tid >> 2);    // 0..255
  int dbase = (tid & 3) * 32;
  int qr = qtile * BM + row;
  if (qr >= Lq) return;

  size_t s0 = (size_t)(h * maxt + tileIdx) * 2;
  size_t s1 = s0 + 1;
  float m0 = pm[s0 * 256 + row], l0 = pl[s0 * 256 + row];
  float m1 = pm[s1 * 256 + row], l1 = pl[s1 * 256 + row];
  float M = fmaxf(m0, m1);
  float w0 = __builtin_amdgcn_exp2f(m0 - M);
  float w1 = __builtin_amdgcn_exp2f(m1 - M);
  float rn = 1.0f / (w0 * l0 + w1 * l1);
  w0 *= rn; w1 *= rn;

  const bf16_t* p0 = pO + s0 * (256 * 128) + row * 128 + dbase;
  const bf16_t* p1 = pO + s1 * (256 * 128) + row * 128 + dbase;
  float* op = out + ((size_t)(s0q + qr) * H + h) * D + dbase;
  #pragma unroll
  for (int j = 0; j < 4; ++j) {
    bf16x8 a = *(const bf16x8*)(p0 + j * 8);
    bf16x8 b = *(const bf16x8*)(p1 + j * 8);
    float4 o0, o1;
    o0.x = w0 * (float)a[0] + w1 * (float)b[0];
    o0.y = w0 * (float)a[1] + w1 * (float)b[1];
    o0.z = w0 * (float)a[2] + w1 * (float)b[2];
    o0.w = w0 * (float)a[3] + w1 * (float)b[3];
    o1.x = w0 * (float)a[4] + w1 * (float)b[4];
    o1.y = w0 * (float)a[5] + w1 * (float)b[5];
    o1.z = w0 * (float)a[6] + w1 * (float)b[6];
    o1.w = w0 * (float)a[7] + w1 * (float)b[7];
    *(float4*)(op + j * 8) = o0;
    *(float4*)(op + j * 8 + 4) = o1;
  }
}

// ---------------- fallback: round-15 single-pass kernel ----------------

__global__ __launch_bounds__(NT, 2)
void fa_varlen15(const float* __restrict__ q,
                 const bf16_t* __restrict__ kb,
                 const bf16_t* __restrict__ vt,
                 const int* __restrict__ cuq,
                 const int* __restrict__ cuk,
                 float* __restrict__ out,
                 int nseq, int maxtiles)
{
  __shared__ alignas(16) bf16_t sK[2][BN * D];
  __shared__ alignas(16) bf16_t sVt[3][8 * 128 * 8];

  const int nwg = gridDim.x;
  const int orig = blockIdx.x;
  const int qq = nwg >> 3, rr = nwg & 7;
  const int xcd = orig & 7;
  const int wgid = (xcd < rr ? xcd * (qq + 1) : rr * (qq + 1) + (xcd - rr) * qq) + (orig >> 3);
  const int tile = wgid % maxtiles;
  const int h = wgid / maxtiles;

  int acc = 0, seq = -1, lt = 0, s0q = 0, s0k = 0, Lq = 0, Lk = 0, Lkp = 0;
  size_t vb = 0;
  for (int s = 0; s < nseq; ++s) {
    int a = cuq[s], b = cuq[s + 1];
    int Ls = b - a;
    int nt = (Ls + BM - 1) / BM;
    int Lks = cuk[s + 1] - cuk[s];
    int Lp = (Lks + 63) & ~63;
    if (tile < acc + nt) {
      seq = s; lt = tile - acc; s0q = a; Lq = Ls;
      s0k = cuk[s]; Lk = Lks; Lkp = Lp;
      break;
    }
    acc += nt; vb += (size_t)H * D * Lp;
  }
  if (seq < 0) return;

  const int q0 = lt * BM;
  const int tid = threadIdx.x;
  const int lane = tid & 63;
  const int lq = lane & 31;
  const int hi = lane >> 5;
  const int warp = tid >> 6;

  const float SC = 0.08838834764831845f * 1.44269504088896340f;

  bf16x8 qf[8];
  {
    int qrow = q0 + warp * 32 + lq; if (qrow >= Lq) qrow = Lq - 1;
    const float* qp = q + ((size_t)(s0q + qrow) * H + h) * D;
    #pragma unroll
    for (int ks = 0; ks < 8; ++ks) {
      const float* p = qp + ks * 16 + hi * 8;
      float4 a = *(const float4*)p, b = *(const float4*)(p + 4);
      bf16x8 r;
      r[0] = (bf16_t)(a.x * SC); r[1] = (bf16_t)(a.y * SC);
      r[2] = (bf16_t)(a.z * SC); r[3] = (bf16_t)(a.w * SC);
      r[4] = (bf16_t)(b.x * SC); r[5] = (bf16_t)(b.y * SC);
      r[6] = (bf16_t)(b.z * SC); r[7] = (bf16_t)(b.w * SC);
      qf[ks] = r;
    }
  }

  const bf16_t* vsrcH = vt + vb + (size_t)h * D * Lkp;

  auto STAGE_K = [&](int tt, int buf) {
    const int kvb = tt * BN;
    #pragma unroll
    for (int i = 0; i < 2; ++i) {
      int g = tid + i * NT;
      int row = g >> 4, cc = g & 15;
      int kvr = kvb + row; if (kvr >= Lk) kvr = Lk - 1;
      const bf16_t* src = kb + ((size_t)(s0k + kvr) * H + h) * D + ((cc ^ (row & 7)) << 3);
      gld_lds16(src, &sK[buf][g * 8]);
    }
  };
  auto STAGE_V = [&](int tt, int buf) {
    const bf16_t* vsrc = vsrcH + (size_t)tt * 8192;
    #pragma unroll
    for (int i = 0; i < 2; ++i) {
      int g = tid + i * NT;
      gld_lds16(vsrc + (size_t)g * 8, &sVt[buf][g * 8]);
    }
  };

  f32x16 oacc[4];
  #pragma unroll
  for (int dt = 0; dt < 4; ++dt)
    #pragma unroll
    for (int r = 0; r < 16; ++r) oacc[dt][r] = 0.f;
  float m = -1e30f, l = 0.f;

  FragU paP, pbP;
  #pragma unroll
  for (int i = 0; i < 4; ++i) { paP.w[i] = 0u; pbP.w[i] = 0u; }
  float alphaP = 1.0f;
  int tP = 0, ctP = 0;

  const int nkv = (Lk + BN - 1) / BN;

  STAGE_K(0, 0);
  STAGE_V(0, 0);
  asm volatile("s_waitcnt vmcnt(0)" ::: "memory");
  __builtin_amdgcn_s_barrier();
  __builtin_amdgcn_sched_barrier(0);

  for (int t = 0; t < nkv; ++t) {
    const int kvb = t * BN;
    int tn = t + 1 < nkv ? t + 1 : nkv - 1;
    STAGE_K(tn, (t + 1) & 1);
    STAGE_V(tn, (t + 1) % 3);

    const bf16_t* sKc = sK[t & 1];
    const bool tail = (kvb + BN > Lk);

    #pragma unroll
    for (int ct = 0; ct < 2; ++ct) {
      f32x16 sa, sb;
      #pragma unroll
      for (int r = 0; r < 16; ++r) { sa[r] = 0.f; sb[r] = 0.f; }
      int krow = ct * 32 + lq;
      __builtin_amdgcn_s_setprio(1);
      #pragma unroll
      for (int ks = 0; ks < 4; ++ks) {
        int posa = (ks * 2 + hi) ^ (krow & 7);
        bf16x8 kfa = *(const bf16x8*)&sKc[krow * 128 + (posa << 3)];
        sa = MFMA32(kfa, qf[ks], sa);
        int posb = ((ks + 4) * 2 + hi) ^ (krow & 7);
        bf16x8 kfb = *(const bf16x8*)&sKc[krow * 128 + (posb << 3)];
        sb = MFMA32(kfb, qf[ks + 4], sb);
      }
      __builtin_amdgcn_s_setprio(0);

      if (__any(alphaP != 1.0f)) {
        #pragma unroll
        for (int r = 0; r < 16; ++r) {
          int cr = (r & 3) + 8 * (r >> 2) + 4 * hi;
          float a2 = __shfl(alphaP, cr);
          #pragma unroll
          for (int dt = 0; dt < 4; ++dt) oacc[dt][r] *= a2;
        }
      }
      {
        const bf16_t* sVp = sVt[tP % 3];
        #pragma unroll
        for (int dt = 0; dt < 4; ++dt) {
          int drow = dt * 32 + lq;
          bf16x8 vf0 = *(const bf16x8*)&sVp[((ctP * 4 + hi) * 128 + drow) << 3];
          oacc[dt] = MFMA32(paP.v, vf0, oacc[dt]);
          bf16x8 vf1 = *(const bf16x8*)&sVp[((ctP * 4 + 2 + hi) * 128 + drow) << 3];
          oacc[dt] = MFMA32(pbP.v, vf1, oacc[dt]);
        }
      }

      f32x16 st;
      #pragma unroll
      for (int r = 0; r < 16; ++r) {
        float x = sa[r] + sb[r];
        if (tail) {
          int kvi = kvb + ct * 32 + (r & 3) + 8 * (r >> 2) + 4 * hi;
          if (kvi >= Lk) x = -1e30f;
        }
        st[r] = x;
      }
      float m0;
      {
        float a0 = fmaxf(st[0], st[1]),  a1 = fmaxf(st[2], st[3]);
        float a2 = fmaxf(st[4], st[5]),  a3 = fmaxf(st[6], st[7]);
        float a4 = fmaxf(st[8], st[9]),  a5 = fmaxf(st[10], st[11]);
        float a6 = fmaxf(st[12], st[13]), a7 = fmaxf(st[14], st[15]);
        float b0 = fmaxf(a0, a1), b1 = fmaxf(a2, a3);
        float b2 = fmaxf(a4, a5), b3 = fmaxf(a6, a7);
        m0 = fmaxf(fmaxf(b0, b1), fmaxf(b2, b3));
      }
      float m1 = fmaxf(m0, xhalf(m0, hi));
      bool trig = m1 > m + 8.0f;
      float mnew = trig ? m1 : m;
      float alpha = __builtin_amdgcn_exp2f(m - mnew);
      m = mnew;

      #pragma unroll
      for (int r = 0; r < 16; ++r)
        st[r] = __builtin_amdgcn_exp2f(st[r] - m);
      float psum;
      {
        float a0 = st[0] + st[1],  a1 = st[2] + st[3];
        float a2 = st[4] + st[5],  a3 = st[6] + st[7];
        float a4 = st[8] + st[9],  a5 = st[10] + st[11];
        float a6 = st[12] + st[13], a7 = st[14] + st[15];
        float b0 = a0 + a1, b1 = a2 + a3, b2 = a4 + a5, b3 = a6 + a7;
        psum = (b0 + b1) + (b2 + b3);
      }
      psum += xhalf(psum, hi);
      l = l * alpha + psum;

      uint32_t c0 = cvtpk_bf16(st[0],  st[1]),  c1 = cvtpk_bf16(st[2],  st[3]);
      uint32_t c2 = cvtpk_bf16(st[4],  st[5]),  c3 = cvtpk_bf16(st[6],  st[7]);
      uint32_t c4 = cvtpk_bf16(st[8],  st[9]),  c5 = cvtpk_bf16(st[10], st[11]);
      uint32_t c6 = cvtpk_bf16(st[12], st[13]), c7 = cvtpk_bf16(st[14], st[15]);
      { auto w2 = __builtin_amdgcn_permlane32_swap(c0, c2, false, false); c0 = w2[0]; c2 = w2[1]; }
      { auto w2 = __builtin_amdgcn_permlane32_swap(c1, c3, false, false); c1 = w2[0]; c3 = w2[1]; }
      { auto w2 = __builtin_amdgcn_permlane32_swap(c4, c6, false, false); c4 = w2[0]; c6 = w2[1]; }
      { auto w2 = __builtin_amdgcn_permlane32_swap(c5, c7, false, false); c5 = w2[0]; c7 = w2[1]; }
      paP.w[0] = c0; paP.w[1] = c1; paP.w[2] = c2; paP.w[3] = c3;
      pbP.w[0] = c4; pbP.w[1] = c5; pbP.w[2] = c6; pbP.w[3] = c7;
      alphaP = alpha; tP = t; ctP = ct;
    }

    asm volatile("s_waitcnt vmcnt(2)" ::: "memory");
    __builtin_amdgcn_s_barrier();
    __builtin_amdgcn_sched_barrier(0);
  }

  if (__any(alphaP != 1.0f)) {
    #pragma unroll
    for (int r = 0; r < 16; ++r) {
      int cr = (r & 3) + 8 * (r >> 2) + 4 * hi;
      float a2 = __shfl(alphaP, cr);
      #pragma unroll
      for (int dt = 0; dt < 4; ++dt) oacc[dt][r] *= a2;
    }
  }
  {
    const bf16_t* sVp = sVt[tP % 3];
    #pragma unroll
    for (int dt = 0; dt < 4; ++dt) {
      int drow = dt * 32 + lq;
      bf16x8 vf0 = *(const bf16x8*)&sVp[((ctP * 4 + hi) * 128 + drow) << 3];
      oacc[dt] = MFMA32(paP.v, vf0, oacc[dt]);
      bf16x8 vf1 = *(const bf16x8*)&sVp[((ctP * 4 + 2 + hi) * 128 + drow) << 3];
      oacc[dt] = MFMA32(pbP.v, vf1, oacc[dt]);
    }
  }

  #pragma unroll
  for (int r = 0; r < 16; ++r) {
    int cr = (r & 3) + 8 * (r >> 2) + 4 * hi;
    int qr = q0 + warp * 32 + cr;
    float lcr = __shfl(l, cr);
    if (qr < Lq) {
      float rn = 1.0f / lcr;
      float* op = out + ((size_t)(s0q + qr) * H + h) * D + lq;
      #pragma unroll
      for (int dt = 0; dt < 4; ++dt)
        op[dt * 32] = oacc[dt][r] * rn;
    }
  }
}

extern "C" void kernel_launch(void* const* d_in, const int* in_sizes, int n_in,
                              void* d_out, int out_size, void* d_ws, size_t ws_size,
                              hipStream_t stream) {
  const float* q = (const float*)d_in[0];
  const float* k = (const float*)d_in[1];
  const float* v = (const float*)d_in[2];
  const int* cuq = (const int*)d_in[3];
  const int* cuk = (const int*)d_in[4];
  float* out = (float*)d_out;

  int total = in_sizes[0] / (H * D);
  int nseq = in_sizes[3] - 1;
  int maxt = (total + BM - 1) / BM + nseq;   // upper bound on Σ ceil(L/256)
  int upb = 2 * maxt;                        // units-per-head upper bound

  size_t needK = (size_t)in_sizes[1] * 2;
  size_t needV = (size_t)in_sizes[2] * 2 + (size_t)nseq * 64 * H * D * 2 + 256;
  size_t slots = (size_t)maxt * H * 2;
  size_t needPO = slots * 256 * 128 * 2;
  size_t needML = slots * 256 * 4 * 2;

  if (ws_size >= needK + needV + needPO + needML + 256) {
    bf16_t* kb = (bf16_t*)d_ws;
    bf16_t* vtb = (bf16_t*)((char*)d_ws + needK);
    bf16_t* pO = (bf16_t*)((char*)d_ws + needK + needV);
    float* pm = (float*)((char*)d_ws + needK + needV + needPO);
    float* pl = pm + slots * 256;

    conv_k<<<1024, 256, 0, stream>>>(k, kb, in_sizes[1] / 8);
    int maxvt = (total + 63) / 64 + nseq;
    conv_vt<<<dim3(maxvt, H), 128, 0, stream>>>(v, vtb, cuk, nseq);
    fa_split<<<dim3(upb * H), NT, 0, stream>>>(q, kb, vtb, cuq, cuk, out,
                                               pO, pm, pl, nseq, maxt, upb);
    fa_combine<<<dim3(maxt * H * 4), 256, 0, stream>>>(cuq, cuk, pO, pm, pl,
                                                       out, nseq, maxt);
  } else if (ws_size >= needK + needV) {
    bf16_t* kb = (bf16_t*)d_ws;
    bf16_t* vtb = (bf16_t*)((char*)d_ws + needK);
    conv_k<<<1024, 256, 0, stream>>>(k, kb, in_sizes[1] / 8);
    int maxvt = (total + 63) / 64 + nseq;
    conv_vt<<<dim3(maxvt, H), 128, 0, stream>>>(v, vtb, cuk, nseq);
    fa_varlen15<<<dim3(maxt * H), NT, 0, stream>>>(q, kb, vtb, cuq, cuk, out, nseq, maxt);
  }
}

// Round 19
// 121.701 us; speedup vs baseline: 1.1964x; 1.1964x over previous
//
#include <hip/hip_runtime.h>
#include <hip/hip_bf16.h>
#include <stdint.h>

#define H 16
#define D 128
#define BM 256      // q rows per block (8 warps x 32)
#define BN 64       // kv rows per tile
#define NT 512

typedef __bf16 bf16_t;
typedef bf16_t bf16x8 __attribute__((ext_vector_type(8)));
typedef float f32x16 __attribute__((ext_vector_type(16)));

#define MFMA32(a, b, c) __builtin_amdgcn_mfma_f32_32x32x16_bf16(a, b, c, 0, 0, 0)

union FragU { uint32_t w[4]; bf16x8 v; };

static __device__ __forceinline__ uint32_t cvtpk_bf16(float lo, float hi) {
  uint32_t r;
  asm("v_cvt_pk_bf16_f32 %0, %1, %2" : "=v"(r) : "v"(lo), "v"(hi));
  return r;
}

static __device__ __forceinline__ void gld_lds16(const bf16_t* g, bf16_t* l) {
  __builtin_amdgcn_global_load_lds(
      (const __attribute__((address_space(1))) void*)g,
      (__attribute__((address_space(3))) void*)l, 16, 0, 0);
}

// cross-half exchange: lane i receives v[i^32] (verified round 15)
static __device__ __forceinline__ float xhalf(float v, int hi) {
  uint32_t b = __builtin_bit_cast(uint32_t, v);
  auto p = __builtin_amdgcn_permlane32_swap(b, b, false, false);
  uint32_t o = hi ? p[0] : p[1];
  return __builtin_bit_cast(float, o);
}

// ---------------- convert kernels (one-time per launch) ----------------

__global__ void conv_k(const float* __restrict__ kin, bf16_t* __restrict__ kb, int n8) {
  int i = blockIdx.x * blockDim.x + threadIdx.x;
  int stride = gridDim.x * blockDim.x;
  for (; i < n8; i += stride) {
    const float* p = kin + (size_t)i * 8;
    float4 a = *(const float4*)p, b = *(const float4*)(p + 4);
    bf16x8 w;
    w[0] = (bf16_t)a.x; w[1] = (bf16_t)a.y; w[2] = (bf16_t)a.z; w[3] = (bf16_t)a.w;
    w[4] = (bf16_t)b.x; w[5] = (bf16_t)b.y; w[6] = (bf16_t)b.z; w[7] = (bf16_t)b.w;
    *(bf16x8*)(kb + (size_t)i * 8) = w;
  }
}

// V[token][h][d] f32 -> per (seq,head): padded-64 kv tiles, each 64-kv tile is
// 1024 slots of 8 bf16: slot (c*128 + d) holds V[kv = tt*64 + c*8 .. +7][d].
__global__ void conv_vt(const float* __restrict__ v, bf16_t* __restrict__ vt,
                        const int* __restrict__ cuk, int nseq) {
  int tile = blockIdx.x, h = blockIdx.y;
  int acc = 0, seq = -1, lt = 0, s0k = 0, Lk = 0, Lkp = 0;
  size_t vb = 0;
  for (int s = 0; s < nseq; ++s) {
    int Ls = cuk[s + 1] - cuk[s];
    int Lp = (Ls + 63) & ~63;
    int nt = Lp / 64;
    if (tile < acc + nt) { seq = s; lt = tile - acc; s0k = cuk[s]; Lk = Ls; Lkp = Lp; break; }
    acc += nt; vb += (size_t)H * D * Lp;
  }
  if (seq < 0) return;
  int kv0 = lt * 64;
  int d = threadIdx.x;            // 0..127, coalesced reads
  bf16x8 w[8];
  #pragma unroll
  for (int j = 0; j < 64; ++j) {
    int kv = kv0 + j;
    int kvc = kv < Lk ? kv : Lk - 1;
    float val = v[((size_t)(s0k + kvc) * H + h) * D + d];
    w[j >> 3][j & 7] = (bf16_t)val;
  }
  bf16_t* dstT = vt + vb + (size_t)h * D * Lkp + (size_t)lt * 8192;
  #pragma unroll
  for (int c = 0; c < 8; ++c)
    *(bf16x8*)(dstT + ((size_t)c * 128 + d) * 8) = w[c];
}

// ---------------- main kernel: T15 pipeline + permlane reductions ----------------

__global__ __launch_bounds__(NT, 2)
void fa_varlen19(const float* __restrict__ q,
                 const bf16_t* __restrict__ kb,
                 const bf16_t* __restrict__ vt,
                 const int* __restrict__ cuq,
                 const int* __restrict__ cuk,
                 float* __restrict__ out,
                 int nseq, int maxtiles)
{
  __shared__ alignas(16) bf16_t sK[2][BN * D];        // 2 x 16KB, swizzled row-major
  __shared__ alignas(16) bf16_t sVt[3][8 * 128 * 8];  // 3 x 16KB, chunk-major [c][d][8]
  // total LDS = 80KB -> 2 blocks/CU

  // ---- bijective XCD-chunked remap (m204) ----
  const int nwg = gridDim.x;
  const int orig = blockIdx.x;
  const int qq = nwg >> 3, rr = nwg & 7;
  const int xcd = orig & 7;
  const int wgid = (xcd < rr ? xcd * (qq + 1) : rr * (qq + 1) + (xcd - rr) * qq) + (orig >> 3);
  const int tile = wgid % maxtiles;
  const int h = wgid / maxtiles;

  int acc = 0, seq = -1, lt = 0, s0q = 0, s0k = 0, Lq = 0, Lk = 0, Lkp = 0;
  size_t vb = 0;
  for (int s = 0; s < nseq; ++s) {
    int a = cuq[s], b = cuq[s + 1];
    int Ls = b - a;
    int nt = (Ls + BM - 1) / BM;
    int Lks = cuk[s + 1] - cuk[s];
    int Lp = (Lks + 63) & ~63;
    if (tile < acc + nt) {
      seq = s; lt = tile - acc; s0q = a; Lq = Ls;
      s0k = cuk[s]; Lk = Lks; Lkp = Lp;
      break;
    }
    acc += nt; vb += (size_t)H * D * Lp;
  }
  if (seq < 0) return;

  const int q0 = lt * BM;
  const int tid = threadIdx.x;
  const int lane = tid & 63;
  const int lq = lane & 31;
  const int hi = lane >> 5;

  const float SC = 0.08838834764831845f * 1.44269504088896340f; // folded into Q

  // ---- Q fragments straight from global f32, pre-scaled by SC ----
  bf16x8 qf[8];
  {
    int warp = tid >> 6;
    int qrow = q0 + warp * 32 + lq; if (qrow >= Lq) qrow = Lq - 1;
    const float* qp = q + ((size_t)(s0q + qrow) * H + h) * D;
    #pragma unroll
    for (int ks = 0; ks < 8; ++ks) {
      const float* p = qp + ks * 16 + hi * 8;
      float4 a = *(const float4*)p, b = *(const float4*)(p + 4);
      bf16x8 r;
      r[0] = (bf16_t)(a.x * SC); r[1] = (bf16_t)(a.y * SC);
      r[2] = (bf16_t)(a.z * SC); r[3] = (bf16_t)(a.w * SC);
      r[4] = (bf16_t)(b.x * SC); r[5] = (bf16_t)(b.y * SC);
      r[6] = (bf16_t)(b.z * SC); r[7] = (bf16_t)(b.w * SC);
      qf[ks] = r;
    }
  }

  const bf16_t* vsrcH = vt + vb + (size_t)h * D * Lkp;

  auto STAGE_K = [&](int tt, int buf) {
    const int kvb = tt * BN;
    #pragma unroll
    for (int i = 0; i < 2; ++i) {
      int g = tid + i * NT;                 // 0..1023
      int row = g >> 4, cc = g & 15;
      int kvr = kvb + row; if (kvr >= Lk) kvr = Lk - 1;
      const bf16_t* src = kb + ((size_t)(s0k + kvr) * H + h) * D + ((cc ^ (row & 7)) << 3);
      gld_lds16(src, &sK[buf][g * 8]);
    }
  };
  auto STAGE_V = [&](int tt, int buf) {
    const bf16_t* vsrc = vsrcH + (size_t)tt * 8192;
    #pragma unroll
    for (int i = 0; i < 2; ++i) {
      int g = tid + i * NT;
      gld_lds16(vsrc + (size_t)g * 8, &sVt[buf][g * 8]);
    }
  };

  f32x16 oacc[4];
  #pragma unroll
  for (int dt = 0; dt < 4; ++dt)
    #pragma unroll
    for (int r = 0; r < 16; ++r) oacc[dt][r] = 0.f;
  float m = -1e30f, l = 0.f;

  // pipeline state: P-frags / alpha / location of the PREVIOUS phase
  FragU paP, pbP;
  #pragma unroll
  for (int i = 0; i < 4; ++i) { paP.w[i] = 0u; pbP.w[i] = 0u; }
  float alphaP = 1.0f;
  int tP = 0, ctP = 0;

  const int nkv = (Lk + BN - 1) / BN;

  STAGE_K(0, 0);
  STAGE_V(0, 0);
  asm volatile("s_waitcnt vmcnt(0)" ::: "memory");
  __builtin_amdgcn_s_barrier();
  __builtin_amdgcn_sched_barrier(0);

  for (int t = 0; t < nkv; ++t) {
    const int kvb = t * BN;
    int tn = t + 1 < nkv ? t + 1 : nkv - 1;
    STAGE_K(tn, (t + 1) & 1);       // K first (drained by end-of-iter vmcnt(2))
    STAGE_V(tn, (t + 1) % 3);       // V second (may stay in flight 2 iters)

    const bf16_t* sKc = sK[t & 1];
    const bool tail = (kvb + BN > Lk);

    #pragma unroll
    for (int ct = 0; ct < 2; ++ct) {
      // ---- QK^T(p) swapped, 2 independent MFMA chains ----
      f32x16 sa, sb;
      #pragma unroll
      for (int r = 0; r < 16; ++r) { sa[r] = 0.f; sb[r] = 0.f; }
      int krow = ct * 32 + lq;
      __builtin_amdgcn_s_setprio(1);
      #pragma unroll
      for (int ks = 0; ks < 4; ++ks) {
        int posa = (ks * 2 + hi) ^ (krow & 7);
        bf16x8 kfa = *(const bf16x8*)&sKc[krow * 128 + (posa << 3)];
        sa = MFMA32(kfa, qf[ks], sa);
        int posb = ((ks + 4) * 2 + hi) ^ (krow & 7);
        bf16x8 kfb = *(const bf16x8*)&sKc[krow * 128 + (posb << 3)];
        sb = MFMA32(kfb, qf[ks + 4], sb);
      }
      __builtin_amdgcn_s_setprio(0);

      // ---- PV(p-1): rescale + 8 MFMAs; register-independent of softmax(p) ----
      if (__any(alphaP != 1.0f)) {
        #pragma unroll
        for (int r = 0; r < 16; ++r) {
          int cr = (r & 3) + 8 * (r >> 2) + 4 * hi;
          float a2 = __shfl(alphaP, cr);
          #pragma unroll
          for (int dt = 0; dt < 4; ++dt) oacc[dt][r] *= a2;
        }
      }
      {
        const bf16_t* sVp = sVt[tP % 3];
        #pragma unroll
        for (int dt = 0; dt < 4; ++dt) {
          int drow = dt * 32 + lq;
          bf16x8 vf0 = *(const bf16x8*)&sVp[((ctP * 4 + hi) * 128 + drow) << 3];
          oacc[dt] = MFMA32(paP.v, vf0, oacc[dt]);
          bf16x8 vf1 = *(const bf16x8*)&sVp[((ctP * 4 + 2 + hi) * 128 + drow) << 3];
          oacc[dt] = MFMA32(pbP.v, vf1, oacc[dt]);
        }
      }

      // ---- softmax(p), exp2 domain, defer-max THR=8, permlane reductions ----
      f32x16 st;
      #pragma unroll
      for (int r = 0; r < 16; ++r) {
        float x = sa[r] + sb[r];
        if (tail) {
          int kvi = kvb + ct * 32 + (r & 3) + 8 * (r >> 2) + 4 * hi;
          if (kvi >= Lk) x = -1e30f;
        }
        st[r] = x;
      }
      float m0;
      {
        float a0 = fmaxf(st[0], st[1]),  a1 = fmaxf(st[2], st[3]);
        float a2 = fmaxf(st[4], st[5]),  a3 = fmaxf(st[6], st[7]);
        float a4 = fmaxf(st[8], st[9]),  a5 = fmaxf(st[10], st[11]);
        float a6 = fmaxf(st[12], st[13]), a7 = fmaxf(st[14], st[15]);
        float b0 = fmaxf(a0, a1), b1 = fmaxf(a2, a3);
        float b2 = fmaxf(a4, a5), b3 = fmaxf(a6, a7);
        m0 = fmaxf(fmaxf(b0, b1), fmaxf(b2, b3));
      }
      float m1 = fmaxf(m0, xhalf(m0, hi));     // VALU cross-half, not ds_bpermute
      bool trig = m1 > m + 8.0f;
      float mnew = trig ? m1 : m;
      float alpha = __builtin_amdgcn_exp2f(m - mnew);
      m = mnew;

      #pragma unroll
      for (int r = 0; r < 16; ++r)
        st[r] = __builtin_amdgcn_exp2f(st[r] - m);
      float psum;
      {
        float a0 = st[0] + st[1],  a1 = st[2] + st[3];
        float a2 = st[4] + st[5],  a3 = st[6] + st[7];
        float a4 = st[8] + st[9],  a5 = st[10] + st[11];
        float a6 = st[12] + st[13], a7 = st[14] + st[15];
        float b0 = a0 + a1, b1 = a2 + a3, b2 = a4 + a5, b3 = a6 + a7;
        psum = (b0 + b1) + (b2 + b3);
      }
      psum += xhalf(psum, hi);                 // VALU cross-half
      l = l * alpha + psum;

      // ---- pack P(p) -> bf16 A-frags; becomes "previous" for next phase ----
      uint32_t c0 = cvtpk_bf16(st[0],  st[1]),  c1 = cvtpk_bf16(st[2],  st[3]);
      uint32_t c2 = cvtpk_bf16(st[4],  st[5]),  c3 = cvtpk_bf16(st[6],  st[7]);
      uint32_t c4 = cvtpk_bf16(st[8],  st[9]),  c5 = cvtpk_bf16(st[10], st[11]);
      uint32_t c6 = cvtpk_bf16(st[12], st[13]), c7 = cvtpk_bf16(st[14], st[15]);
      { auto rr2 = __builtin_amdgcn_permlane32_swap(c0, c2, false, false); c0 = rr2[0]; c2 = rr2[1]; }
      { auto rr2 = __builtin_amdgcn_permlane32_swap(c1, c3, false, false); c1 = rr2[0]; c3 = rr2[1]; }
      { auto rr2 = __builtin_amdgcn_permlane32_swap(c4, c6, false, false); c4 = rr2[0]; c6 = rr2[1]; }
      { auto rr2 = __builtin_amdgcn_permlane32_swap(c5, c7, false, false); c5 = rr2[0]; c7 = rr2[1]; }
      paP.w[0] = c0; paP.w[1] = c1; paP.w[2] = c2; paP.w[3] = c3;
      pbP.w[0] = c4; pbP.w[1] = c5; pbP.w[2] = c6; pbP.w[3] = c7;
      alphaP = alpha; tP = t; ctP = ct;
    }

    // K(t+1) landed (drain-all-but-2, V(t+1) stays flying); then barrier
    asm volatile("s_waitcnt vmcnt(2)" ::: "memory");
    __builtin_amdgcn_s_barrier();
    __builtin_amdgcn_sched_barrier(0);
  }

  // ---- final pipelined phase: PV(nkv-1, ct=1) ----
  if (__any(alphaP != 1.0f)) {
    #pragma unroll
    for (int r = 0; r < 16; ++r) {
      int cr = (r & 3) + 8 * (r >> 2) + 4 * hi;
      float a2 = __shfl(alphaP, cr);
      #pragma unroll
      for (int dt = 0; dt < 4; ++dt) oacc[dt][r] *= a2;
    }
  }
  {
    const bf16_t* sVp = sVt[tP % 3];
    #pragma unroll
    for (int dt = 0; dt < 4; ++dt) {
      int drow = dt * 32 + lq;
      bf16x8 vf0 = *(const bf16x8*)&sVp[((ctP * 4 + hi) * 128 + drow) << 3];
      oacc[dt] = MFMA32(paP.v, vf0, oacc[dt]);
      bf16x8 vf1 = *(const bf16x8*)&sVp[((ctP * 4 + 2 + hi) * 128 + drow) << 3];
      oacc[dt] = MFMA32(pbP.v, vf1, oacc[dt]);
    }
  }

  // ---- epilogue: broadcast l via shfl, normalize, coalesced store ----
  #pragma unroll
  for (int r = 0; r < 16; ++r) {
    int cr = (r & 3) + 8 * (r >> 2) + 4 * hi;
    int warp = tid >> 6;
    int qr = q0 + warp * 32 + cr;
    float lcr = __shfl(l, cr);
    if (qr < Lq) {
      float rn = 1.0f / lcr;
      float* op = out + ((size_t)(s0q + qr) * H + h) * D + lq;
      #pragma unroll
      for (int dt = 0; dt < 4; ++dt)
        op[dt * 32] = oacc[dt][r] * rn;
    }
  }
}

extern "C" void kernel_launch(void* const* d_in, const int* in_sizes, int n_in,
                              void* d_out, int out_size, void* d_ws, size_t ws_size,
                              hipStream_t stream) {
  const float* q = (const float*)d_in[0];
  const float* k = (const float*)d_in[1];
  const float* v = (const float*)d_in[2];
  const int* cuq = (const int*)d_in[3];
  const int* cuk = (const int*)d_in[4];
  float* out = (float*)d_out;

  int total = in_sizes[0] / (H * D);
  int nseq = in_sizes[3] - 1;
  int maxt = (total + BM - 1) / BM + nseq;

  size_t needK = (size_t)in_sizes[1] * 2;

  bf16_t* kb = (bf16_t*)d_ws;
  bf16_t* vtb = (bf16_t*)((char*)d_ws + needK);

  conv_k<<<1024, 256, 0, stream>>>(k, kb, in_sizes[1] / 8);
  int maxvt = (total + 63) / 64 + nseq;
  conv_vt<<<dim3(maxvt, H), 128, 0, stream>>>(v, vtb, cuk, nseq);
  fa_varlen19<<<dim3(maxt * H), NT, 0, stream>>>(q, kb, vtb, cuq, cuk, out, nseq, maxt);
}